// Round 1
// baseline (435.980 us; speedup 1.0000x reference)
//
#include <hip/hip_runtime.h>

typedef unsigned short u16;
typedef unsigned int u32;
typedef __attribute__((ext_vector_type(8))) short short8;
typedef __attribute__((ext_vector_type(4))) float floatx4;

static constexpr int M = 16384, N = 2048, K = 2048;

// ---- helpers -------------------------------------------------------------

__device__ inline u16 f32_to_bf16(float x) {
    u32 u = __float_as_uint(x);
    u += 0x7FFFu + ((u >> 16) & 1u);
    return (u16)(u >> 16);
}

// RNE round to e4m3 grid; valid for x in [2^-6, 448] (normal e4m3 range,
// guaranteed by the preceding clip). 3 mantissa bits -> round at fp32 bit 20.
__device__ inline float e4m3_rne(float x) {
    u32 u = __float_as_uint(x);
    u += 0x7FFFFu + ((u >> 20) & 1u);
    u &= 0xFFF00000u;
    return __uint_as_float(u);
}

// decode fp4 e2m1 code (4 bits incl. sign) -> float {0,.5,1,1.5,2,3,4,6}*sign
__device__ inline float fp4_dec(u32 c) {
    u32 e = (c >> 1) & 3u;
    float m = (float)(c & 1u);
    float v = e ? (2.0f + m) * (float)(1u << e) * 0.25f : 0.5f * m;
    return (c & 8u) ? -v : v;
}

// reference fp4_121_positive with jnp.round == RNE == rintf
__device__ inline float fp4_round_mag(float a) {
    if (a < 2.0f) return rintf(2.0f * a) * 0.5f;
    if (a < 4.0f) return rintf(a);
    return 2.0f * rintf(a * 0.5f);
}

__device__ inline float pts_from_amax(float amax) {
    // clip(amax / 448, 2^-6, 448); true IEEE division to match reference
    return fminf(fmaxf(amax / 448.0f, 0.015625f), 448.0f);
}

// ---- kernel 1: global amax ----------------------------------------------

__global__ void amax_kernel(const float4* __restrict__ x, u32* __restrict__ out, int n4) {
    int idx = blockIdx.x * blockDim.x + threadIdx.x;
    int stride = gridDim.x * blockDim.x;
    float m = 0.0f;
    for (int i = idx; i < n4; i += stride) {
        float4 v = x[i];
        m = fmaxf(m, fmaxf(fmaxf(fabsf(v.x), fabsf(v.y)), fmaxf(fabsf(v.z), fabsf(v.w))));
    }
#pragma unroll
    for (int off = 32; off > 0; off >>= 1)
        m = fmaxf(m, __shfl_down(m, off));
    __shared__ float sm[4];
    if ((threadIdx.x & 63) == 0) sm[threadIdx.x >> 6] = m;
    __syncthreads();
    if (threadIdx.x == 0) {
        m = fmaxf(fmaxf(sm[0], sm[1]), fmaxf(sm[2], sm[3]));
        atomicMax(out, __float_as_uint(m));  // positive floats monotone as uint
    }
}

// ---- kernel 2: QDQ x -> bf16 A = lp * sbs (exact in bf16) ---------------

__global__ void quant_x(const float* __restrict__ x, u16* __restrict__ aq,
                        const u32* __restrict__ amax_bits, int nblk) {
    int idx = blockIdx.x * blockDim.x + threadIdx.x;
    if (idx >= nblk) return;
    const float4* xp = (const float4*)(x + (size_t)idx * 16);
    float4 v[4];
#pragma unroll
    for (int i = 0; i < 4; i++) v[i] = xp[i];

    float bm = 0.0f;
#pragma unroll
    for (int i = 0; i < 4; i++)
        bm = fmaxf(bm, fmaxf(fmaxf(fabsf(v[i].x), fabsf(v[i].y)),
                             fmaxf(fabsf(v[i].z), fabsf(v[i].w))));

    float pts = pts_from_amax(__uint_as_float(*amax_bits));
    float bs = bm / 6.0f;                                    // block_scale
    float sbs = e4m3_rne(fminf(fmaxf(bs / pts, 0.015625f), 448.0f));
    float ts = pts * sbs;                                    // total_scale

    u16 o[16];
    const float* vf = (const float*)v;
#pragma unroll
    for (int i = 0; i < 16; i++) {
        float s = vf[i] / ts;                                // IEEE div, matches ref
        s = fminf(fmaxf(s, -6.0f), 6.0f);
        float lp = copysignf(fp4_round_mag(fabsf(s)), s);
        o[i] = f32_to_bf16(lp * sbs);                        // exact product
    }
    uint4* op = (uint4*)(aq + (size_t)idx * 16);
    op[0] = ((const uint4*)o)[0];
    op[1] = ((const uint4*)o)[1];
}

// ---- kernel 3: dequant packed weight -> bf16 B = w4 * wsc (exact) -------

__global__ void dequant_w(const int* __restrict__ wp, const float* __restrict__ wsc,
                          const float* __restrict__ wgs, u16* __restrict__ wq, int total) {
    int idx = blockIdx.x * blockDim.x + threadIdx.x;
    if (idx >= total) return;
    constexpr int Khalf = K / 2;                 // 1024
    int n = idx >> 10;
    int kb = idx & (Khalf - 1);
    u32 byte = (u32)wp[idx] & 0xFFu;
    float scale = wsc[(size_t)n * (K / 16) + (kb >> 3)] / wgs[0];
    float lo = fp4_dec(byte & 0xFu) * scale;
    float hi = fp4_dec((byte >> 4) & 0xFu) * scale;
    u32 out = (u32)f32_to_bf16(lo) | ((u32)f32_to_bf16(hi) << 16);
    ((u32*)wq)[idx] = out;                       // wq[n*K + 2*kb .. +1]
}

// ---- kernel 4: bf16 GEMM, C[m,n] = pts * sum_k A[m,k]*B[n,k] ------------

#define GLDS(g, l)                                                              \
    __builtin_amdgcn_global_load_lds(                                           \
        (const __attribute__((address_space(1))) unsigned int*)(g),             \
        (__attribute__((address_space(3))) unsigned int*)(l), 16, 0, 0)

__global__ __launch_bounds__(256, 3) void gemm_bt(
    const u16* __restrict__ A, const u16* __restrict__ B,
    float* __restrict__ C, const u32* __restrict__ amax_bits)
{
    __shared__ u16 lA[128 * 32];
    __shared__ u16 lB[128 * 32];

    const int tid = threadIdx.x;
    const int w = tid >> 6, lane = tid & 63;
    const int bm = blockIdx.x >> 4;          // N/128 = 16
    const int bn = blockIdx.x & 15;
    const int wm = w >> 1, wn = w & 1;
    const int r = lane & 15, q = lane >> 4;

    floatx4 acc[4][4] = {};

    // staging: per wave, 2 x 16-row chunks for A and B; lane i -> row i/4,
    // 16B chunk (i%4) within the 64-byte (32 x bf16) row. LDS dest must be
    // uniform-base + lane*16 (global_load_lds constraint) -> row-major, no pad.
    const int srow = lane >> 2;
    const int scol = (lane & 3) * 8;
    const u16* gA0 = A + (size_t)(bm * 128 + w * 32 + srow) * K + scol;
    const u16* gA1 = gA0 + (size_t)16 * K;
    const u16* gB0 = B + (size_t)(bn * 128 + w * 32 + srow) * K + scol;
    const u16* gB1 = gB0 + (size_t)16 * K;
    u16* lA0 = &lA[(w * 32) * 32];
    u16* lA1 = &lA[(w * 32 + 16) * 32];
    u16* lB0 = &lB[(w * 32) * 32];
    u16* lB1 = &lB[(w * 32 + 16) * 32];

    for (int kt = 0; kt < K; kt += 32) {
        GLDS(gA0 + kt, lA0);
        GLDS(gA1 + kt, lA1);
        GLDS(gB0 + kt, lB0);
        GLDS(gB1 + kt, lB1);
        __syncthreads();   // compiler emits vmcnt(0) drain before barrier

        short8 af[4], bf[4];
#pragma unroll
        for (int i = 0; i < 4; i++)
            af[i] = *(const short8*)&lA[(wm * 64 + i * 16 + r) * 32 + q * 8];
#pragma unroll
        for (int j = 0; j < 4; j++)
            bf[j] = *(const short8*)&lB[(wn * 64 + j * 16 + r) * 32 + q * 8];

#pragma unroll
        for (int i = 0; i < 4; i++)
#pragma unroll
            for (int j = 0; j < 4; j++)
                acc[i][j] = __builtin_amdgcn_mfma_f32_16x16x32_bf16(
                    af[i], bf[j], acc[i][j], 0, 0, 0);

        __syncthreads();
    }

    float pts = pts_from_amax(__uint_as_float(*amax_bits));

    // C/D layout (verified m89/m91): col = lane&15, row = (lane>>4)*4 + reg
    float* Cb = C + (size_t)(bm * 128 + wm * 64 + q * 4) * N + bn * 128 + wn * 64 + r;
#pragma unroll
    for (int i = 0; i < 4; i++)
#pragma unroll
        for (int j = 0; j < 4; j++)
#pragma unroll
            for (int t = 0; t < 4; t++)
                Cb[(size_t)(i * 16 + t) * N + j * 16] = pts * acc[i][j][t];
}

// ---- launch --------------------------------------------------------------

extern "C" void kernel_launch(void* const* d_in, const int* in_sizes, int n_in,
                              void* d_out, int out_size, void* d_ws, size_t ws_size,
                              hipStream_t stream) {
    const float* x   = (const float*)d_in[0];
    const int*   wp  = (const int*)d_in[1];
    const float* wsc = (const float*)d_in[2];
    const float* wgs = (const float*)d_in[3];
    float* out = (float*)d_out;

    // workspace layout: [0..3] amax bits (zeroed), A bf16 at +256, B bf16 after
    u32* amax_ws = (u32*)d_ws;
    u16* aq = (u16*)((char*)d_ws + 256);
    u16* wq = aq + (size_t)M * K;

    hipMemsetAsync(d_ws, 0, 4, stream);
    amax_kernel<<<4096, 256, 0, stream>>>((const float4*)x, amax_ws, M * K / 4);
    quant_x<<<(M * K / 16) / 256, 256, 0, stream>>>(x, aq, amax_ws, M * K / 16);
    dequant_w<<<(N * (K / 2)) / 256, 256, 0, stream>>>(wp, wsc, wgs, wq, N * (K / 2));
    gemm_bt<<<(M / 128) * (N / 128), 256, 0, stream>>>(aq, wq, out, amax_ws);
}

// Round 2
// 413.166 us; speedup vs baseline: 1.0552x; 1.0552x over previous
//
#include <hip/hip_runtime.h>

typedef unsigned short u16;
typedef unsigned int u32;
typedef __attribute__((ext_vector_type(8))) short short8;
typedef __attribute__((ext_vector_type(4))) float floatx4;

static constexpr int M = 16384, N = 2048, K = 2048;

// ---- helpers -------------------------------------------------------------

__device__ inline u16 f32_to_bf16(float x) {
    u32 u = __float_as_uint(x);
    u += 0x7FFFu + ((u >> 16) & 1u);
    return (u16)(u >> 16);
}

// RNE round to e4m3 grid; valid for x in [2^-6, 448] (normal e4m3 range,
// guaranteed by the preceding clip). 3 mantissa bits -> round at fp32 bit 20.
__device__ inline float e4m3_rne(float x) {
    u32 u = __float_as_uint(x);
    u += 0x7FFFFu + ((u >> 20) & 1u);
    u &= 0xFFF00000u;
    return __uint_as_float(u);
}

// decode fp4 e2m1 code (4 bits incl. sign) -> float {0,.5,1,1.5,2,3,4,6}*sign
__device__ inline float fp4_dec(u32 c) {
    u32 e = (c >> 1) & 3u;
    float m = (float)(c & 1u);
    float v = e ? (2.0f + m) * (float)(1u << e) * 0.25f : 0.5f * m;
    return (c & 8u) ? -v : v;
}

// reference fp4_121_positive with jnp.round == RNE == rintf
__device__ inline float fp4_round_mag(float a) {
    if (a < 2.0f) return rintf(2.0f * a) * 0.5f;
    if (a < 4.0f) return rintf(a);
    return 2.0f * rintf(a * 0.5f);
}

__device__ inline float pts_from_amax(float amax) {
    // clip(amax / 448, 2^-6, 448); true IEEE division to match reference
    return fminf(fmaxf(amax / 448.0f, 0.015625f), 448.0f);
}

// ---- kernel 1a: per-block partial amax (no atomics) ---------------------

__global__ void amax_part(const float4* __restrict__ x, float* __restrict__ part, int n4) {
    int idx = blockIdx.x * blockDim.x + threadIdx.x;
    int stride = gridDim.x * blockDim.x;
    float m = 0.0f;
    for (int i = idx; i < n4; i += stride) {
        float4 v = x[i];
        m = fmaxf(m, fmaxf(fmaxf(fabsf(v.x), fabsf(v.y)), fmaxf(fabsf(v.z), fabsf(v.w))));
    }
#pragma unroll
    for (int off = 32; off > 0; off >>= 1)
        m = fmaxf(m, __shfl_down(m, off));
    __shared__ float sm[4];
    if ((threadIdx.x & 63) == 0) sm[threadIdx.x >> 6] = m;
    __syncthreads();
    if (threadIdx.x == 0)
        part[blockIdx.x] = fmaxf(fmaxf(sm[0], sm[1]), fmaxf(sm[2], sm[3]));
}

// ---- kernel 1b: finalize amax (1 block, 1024 threads, 2048 partials) ----

__global__ void amax_fin(const float* __restrict__ part, u32* __restrict__ out) {
    int t = threadIdx.x;
    float m = fmaxf(part[t], part[t + 1024]);
#pragma unroll
    for (int off = 32; off > 0; off >>= 1)
        m = fmaxf(m, __shfl_down(m, off));
    __shared__ float sm[16];
    if ((t & 63) == 0) sm[t >> 6] = m;
    __syncthreads();
    if (t < 16) {
        m = sm[t];
#pragma unroll
        for (int off = 8; off > 0; off >>= 1)
            m = fmaxf(m, __shfl_down(m, off));
        if (t == 0) *out = __float_as_uint(m);
    }
}

// ---- kernel 2: QDQ x -> bf16 A = lp * sbs (exact in bf16) ---------------
// Wave-cooperative: 4 lanes per 16-block. Lane i loads float4 at base+i*16B
// (contiguous 1 KiB per wave-instr), shfl_xor(1,2) for block max, writes
// 4 bf16 (8 B) per lane contiguous.

__global__ void quant_x(const float4* __restrict__ x, uint2* __restrict__ aq,
                        const u32* __restrict__ amax_bits, int nvec) {
    int idx = blockIdx.x * blockDim.x + threadIdx.x;
    if (idx >= nvec) return;
    float4 v = x[idx];

    float bm = fmaxf(fmaxf(fabsf(v.x), fabsf(v.y)), fmaxf(fabsf(v.z), fabsf(v.w)));
    bm = fmaxf(bm, __shfl_xor(bm, 1));
    bm = fmaxf(bm, __shfl_xor(bm, 2));   // 4-lane group = one 16-block

    float pts = pts_from_amax(__uint_as_float(*amax_bits));
    float bs = bm / 6.0f;                                    // block_scale
    float sbs = e4m3_rne(fminf(fmaxf(bs / pts, 0.015625f), 448.0f));
    float ts = pts * sbs;                                    // total_scale

    float vf[4] = {v.x, v.y, v.z, v.w};
    u16 o[4];
#pragma unroll
    for (int i = 0; i < 4; i++) {
        float s = vf[i] / ts;                                // IEEE div, matches ref
        s = fminf(fmaxf(s, -6.0f), 6.0f);
        float lp = copysignf(fp4_round_mag(fabsf(s)), s);
        o[i] = f32_to_bf16(lp * sbs);                        // exact product
    }
    aq[idx] = *(const uint2*)o;
}

// ---- kernel 3: dequant packed weight -> bf16 B = w4 * wsc (exact) -------

__global__ void dequant_w(const int* __restrict__ wp, const float* __restrict__ wsc,
                          const float* __restrict__ wgs, u16* __restrict__ wq, int total) {
    int idx = blockIdx.x * blockDim.x + threadIdx.x;
    if (idx >= total) return;
    constexpr int Khalf = K / 2;                 // 1024
    int n = idx >> 10;
    int kb = idx & (Khalf - 1);
    u32 byte = (u32)wp[idx] & 0xFFu;
    float scale = wsc[(size_t)n * (K / 16) + (kb >> 3)] / wgs[0];
    float lo = fp4_dec(byte & 0xFu) * scale;
    float hi = fp4_dec((byte >> 4) & 0xFu) * scale;
    u32 out = (u32)f32_to_bf16(lo) | ((u32)f32_to_bf16(hi) << 16);
    ((u32*)wq)[idx] = out;                       // wq[n*K + 2*kb .. +1]
}

// ---- kernel 4: bf16 GEMM, C[m,n] = pts * sum_k A[m,k]*B[n,k] ------------

#define GLDS(g, l)                                                              \
    __builtin_amdgcn_global_load_lds(                                           \
        (const __attribute__((address_space(1))) unsigned int*)(g),             \
        (__attribute__((address_space(3))) unsigned int*)(l), 16, 0, 0)

__global__ __launch_bounds__(256, 3) void gemm_bt(
    const u16* __restrict__ A, const u16* __restrict__ B,
    float* __restrict__ C, const u32* __restrict__ amax_bits)
{
    __shared__ u16 lA[128 * 32];
    __shared__ u16 lB[128 * 32];

    const int tid = threadIdx.x;
    const int w = tid >> 6, lane = tid & 63;

    // XCD swizzle: blocks dispatch round-robin over 8 XCDs (block i -> XCD i&7).
    // Map so all 16 bn-blocks sharing one bm land on the SAME XCD -> A tile
    // (512 KB) fetched into one L2 instead of 8.
    const int id = blockIdx.x;                   // 2048 blocks
    const int xcd = id & 7;
    const int local = id >> 3;                   // 0..255 per XCD
    const int bm = xcd * 16 + (local >> 4);      // 0..127  (M/128)
    const int bn = local & 15;                   // 0..15   (N/128)

    const int wm = w >> 1, wn = w & 1;
    const int r = lane & 15, q = lane >> 4;

    floatx4 acc[4][4] = {};

    // staging: per wave, 2 x 16-row chunks for A and B; lane i -> row i/4,
    // 16B chunk (i%4) within the 64-byte (32 x bf16) row. LDS dest must be
    // uniform-base + lane*16 (global_load_lds constraint) -> row-major, no pad.
    const int srow = lane >> 2;
    const int scol = (lane & 3) * 8;
    const u16* gA0 = A + (size_t)(bm * 128 + w * 32 + srow) * K + scol;
    const u16* gA1 = gA0 + (size_t)16 * K;
    const u16* gB0 = B + (size_t)(bn * 128 + w * 32 + srow) * K + scol;
    const u16* gB1 = gB0 + (size_t)16 * K;
    u16* lA0 = &lA[(w * 32) * 32];
    u16* lA1 = &lA[(w * 32 + 16) * 32];
    u16* lB0 = &lB[(w * 32) * 32];
    u16* lB1 = &lB[(w * 32 + 16) * 32];

    for (int kt = 0; kt < K; kt += 32) {
        GLDS(gA0 + kt, lA0);
        GLDS(gA1 + kt, lA1);
        GLDS(gB0 + kt, lB0);
        GLDS(gB1 + kt, lB1);
        __syncthreads();   // compiler emits vmcnt(0) drain before barrier

        short8 af[4], bf[4];
#pragma unroll
        for (int i = 0; i < 4; i++)
            af[i] = *(const short8*)&lA[(wm * 64 + i * 16 + r) * 32 + q * 8];
#pragma unroll
        for (int j = 0; j < 4; j++)
            bf[j] = *(const short8*)&lB[(wn * 64 + j * 16 + r) * 32 + q * 8];

#pragma unroll
        for (int i = 0; i < 4; i++)
#pragma unroll
            for (int j = 0; j < 4; j++)
                acc[i][j] = __builtin_amdgcn_mfma_f32_16x16x32_bf16(
                    af[i], bf[j], acc[i][j], 0, 0, 0);

        __syncthreads();
    }

    float pts = pts_from_amax(__uint_as_float(*amax_bits));

    // C/D layout (verified m89/m91): col = lane&15, row = (lane>>4)*4 + reg
    float* Cb = C + (size_t)(bm * 128 + wm * 64 + q * 4) * N + bn * 128 + wn * 64 + r;
#pragma unroll
    for (int i = 0; i < 4; i++)
#pragma unroll
        for (int j = 0; j < 4; j++)
#pragma unroll
            for (int t = 0; t < 4; t++)
                Cb[(size_t)(i * 16 + t) * N + j * 16] = pts * acc[i][j][t];
}

// ---- launch --------------------------------------------------------------

extern "C" void kernel_launch(void* const* d_in, const int* in_sizes, int n_in,
                              void* d_out, int out_size, void* d_ws, size_t ws_size,
                              hipStream_t stream) {
    const float* x   = (const float*)d_in[0];
    const int*   wp  = (const int*)d_in[1];
    const float* wsc = (const float*)d_in[2];
    const float* wgs = (const float*)d_in[3];
    float* out = (float*)d_out;

    // workspace layout:
    //   +0      : amax bits (u32, written by amax_fin)
    //   +64     : 2048 float partial maxima
    //   +16384  : A bf16 [M*K]
    //   then    : B bf16 [N*K]
    u32*   amax_ws = (u32*)d_ws;
    float* part    = (float*)((char*)d_ws + 64);
    u16*   aq      = (u16*)((char*)d_ws + 16384);
    u16*   wq      = aq + (size_t)M * K;

    amax_part<<<2048, 256, 0, stream>>>((const float4*)x, part, M * K / 4);
    amax_fin<<<1, 1024, 0, stream>>>(part, amax_ws);
    quant_x<<<(M * K / 4) / 256, 256, 0, stream>>>((const float4*)x, (uint2*)aq,
                                                   amax_ws, M * K / 4);
    dequant_w<<<(N * (K / 2)) / 256, 256, 0, stream>>>(wp, wsc, wgs, wq, N * (K / 2));
    gemm_bt<<<(M / 128) * (N / 128), 256, 0, stream>>>(aq, wq, out, amax_ws);
}

// Round 3
// 409.344 us; speedup vs baseline: 1.0651x; 1.0093x over previous
//
#include <hip/hip_runtime.h>

typedef unsigned short u16;
typedef unsigned int u32;
typedef __attribute__((ext_vector_type(8))) short short8;
typedef __attribute__((ext_vector_type(4))) float floatx4;

static constexpr int M = 16384, N = 2048, K = 2048;

// ---- helpers -------------------------------------------------------------

__device__ inline u16 f32_to_bf16(float x) {
    u32 u = __float_as_uint(x);
    u += 0x7FFFu + ((u >> 16) & 1u);
    return (u16)(u >> 16);
}

// RNE round to e4m3 grid; valid for x in [2^-6, 448] (normal e4m3 range,
// guaranteed by the preceding clip). 3 mantissa bits -> round at fp32 bit 20.
__device__ inline float e4m3_rne(float x) {
    u32 u = __float_as_uint(x);
    u += 0x7FFFFu + ((u >> 20) & 1u);
    u &= 0xFFF00000u;
    return __uint_as_float(u);
}

// decode fp4 e2m1 code (4 bits incl. sign) -> float {0,.5,1,1.5,2,3,4,6}*sign
__device__ inline float fp4_dec(u32 c) {
    u32 e = (c >> 1) & 3u;
    float m = (float)(c & 1u);
    float v = e ? (2.0f + m) * (float)(1u << e) * 0.25f : 0.5f * m;
    return (c & 8u) ? -v : v;
}

// reference fp4_121_positive with jnp.round == RNE == rintf
__device__ inline float fp4_round_mag(float a) {
    if (a < 2.0f) return rintf(2.0f * a) * 0.5f;
    if (a < 4.0f) return rintf(a);
    return 2.0f * rintf(a * 0.5f);
}

__device__ inline float pts_from_amax(float amax) {
    // clip(amax / 448, 2^-6, 448); true IEEE division to match reference
    return fminf(fmaxf(amax / 448.0f, 0.015625f), 448.0f);
}

// ---- kernel 1a: per-block partial amax (no atomics) ---------------------

__global__ void amax_part(const float4* __restrict__ x, float* __restrict__ part, int n4) {
    int idx = blockIdx.x * blockDim.x + threadIdx.x;
    int stride = gridDim.x * blockDim.x;
    float m = 0.0f;
    for (int i = idx; i < n4; i += stride) {
        float4 v = x[i];
        m = fmaxf(m, fmaxf(fmaxf(fabsf(v.x), fabsf(v.y)), fmaxf(fabsf(v.z), fabsf(v.w))));
    }
#pragma unroll
    for (int off = 32; off > 0; off >>= 1)
        m = fmaxf(m, __shfl_down(m, off));
    __shared__ float sm[4];
    if ((threadIdx.x & 63) == 0) sm[threadIdx.x >> 6] = m;
    __syncthreads();
    if (threadIdx.x == 0)
        part[blockIdx.x] = fmaxf(fmaxf(sm[0], sm[1]), fmaxf(sm[2], sm[3]));
}

// ---- kernel 1b: finalize amax (1 block, 1024 threads, 2048 partials) ----

__global__ void amax_fin(const float* __restrict__ part, u32* __restrict__ out) {
    int t = threadIdx.x;
    float m = fmaxf(part[t], part[t + 1024]);
#pragma unroll
    for (int off = 32; off > 0; off >>= 1)
        m = fmaxf(m, __shfl_down(m, off));
    __shared__ float sm[16];
    if ((t & 63) == 0) sm[t >> 6] = m;
    __syncthreads();
    if (t < 16) {
        m = sm[t];
#pragma unroll
        for (int off = 8; off > 0; off >>= 1)
            m = fmaxf(m, __shfl_down(m, off));
        if (t == 0) *out = __float_as_uint(m);
    }
}

// ---- kernel 2: fused prep ------------------------------------------------
// blocks [0, QB)          : QDQ x -> bf16 A = lp * sbs (exact in bf16)
// blocks [QB, QB + DB)    : dequant packed weight -> bf16 B = w4 * wsc

static constexpr int QB = (M * K / 4) / 256;        // 32768 quant blocks
static constexpr int DB = (N * (K / 2)) / 256;      // 8192 dequant blocks

__global__ void prep(const float4* __restrict__ x, uint2* __restrict__ aq,
                     const u32* __restrict__ amax_bits,
                     const int* __restrict__ wp, const float* __restrict__ wsc,
                     const float* __restrict__ wgs, u16* __restrict__ wq) {
    if (blockIdx.x < QB) {
        // --- quant path: 4 lanes per 16-block, float4 per lane ---
        int idx = blockIdx.x * blockDim.x + threadIdx.x;
        float4 v = x[idx];

        float bm = fmaxf(fmaxf(fabsf(v.x), fabsf(v.y)), fmaxf(fabsf(v.z), fabsf(v.w)));
        bm = fmaxf(bm, __shfl_xor(bm, 1));
        bm = fmaxf(bm, __shfl_xor(bm, 2));   // 4-lane group = one 16-block

        float pts = pts_from_amax(__uint_as_float(*amax_bits));
        float bs = bm / 6.0f;                                    // block_scale
        float sbs = e4m3_rne(fminf(fmaxf(bs / pts, 0.015625f), 448.0f));
        float ts = pts * sbs;                                    // total_scale

        float vf[4] = {v.x, v.y, v.z, v.w};
        u16 o[4];
#pragma unroll
        for (int i = 0; i < 4; i++) {
            float s = vf[i] / ts;                                // IEEE div, matches ref
            s = fminf(fmaxf(s, -6.0f), 6.0f);
            float lp = copysignf(fp4_round_mag(fabsf(s)), s);
            o[i] = f32_to_bf16(lp * sbs);                        // exact product
        }
        aq[idx] = *(const uint2*)o;
    } else {
        // --- weight dequant path ---
        int idx = (blockIdx.x - QB) * blockDim.x + threadIdx.x;
        constexpr int Khalf = K / 2;                 // 1024
        int n = idx >> 10;
        int kb = idx & (Khalf - 1);
        u32 byte = (u32)wp[idx] & 0xFFu;
        float scale = wsc[(size_t)n * (K / 16) + (kb >> 3)] / wgs[0];
        float lo = fp4_dec(byte & 0xFu) * scale;
        float hi = fp4_dec((byte >> 4) & 0xFu) * scale;
        u32 out = (u32)f32_to_bf16(lo) | ((u32)f32_to_bf16(hi) << 16);
        ((u32*)wq)[idx] = out;                       // wq[n*K + 2*kb .. +1]
    }
}

// ---- kernel 3: bf16 GEMM, C[m,n] = pts * sum_k A[m,k]*B[n,k] ------------
// BK=64: two 32-wide k-halves staged per barrier pair -> half the barrier
// drains of BK=32. LDS 4 x 8 KB = 32 KB -> still ~3 blocks/CU.

#define GLDS(g, l)                                                              \
    __builtin_amdgcn_global_load_lds(                                           \
        (const __attribute__((address_space(1))) unsigned int*)(g),             \
        (__attribute__((address_space(3))) unsigned int*)(l), 16, 0, 0)

__global__ __launch_bounds__(256, 3) void gemm_bt(
    const u16* __restrict__ A, const u16* __restrict__ B,
    float* __restrict__ C, const u32* __restrict__ amax_bits)
{
    __shared__ u16 lA[2][128 * 32];   // [k-half][row*32 + col]
    __shared__ u16 lB[2][128 * 32];

    const int tid = threadIdx.x;
    const int w = tid >> 6, lane = tid & 63;

    // XCD swizzle: blocks dispatch round-robin over 8 XCDs (block i -> XCD i&7).
    // All 16 bn-blocks sharing one bm land on the SAME XCD -> A tile fetched
    // into one L2 instead of 8 (FETCH 280->158 MB, verified R2).
    const int id = blockIdx.x;                   // 2048 blocks
    const int xcd = id & 7;
    const int local = id >> 3;                   // 0..255 per XCD
    const int bm = xcd * 16 + (local >> 4);      // 0..127  (M/128)
    const int bn = local & 15;                   // 0..15   (N/128)

    const int wm = w >> 1, wn = w & 1;
    const int r = lane & 15, q = lane >> 4;

    floatx4 acc[4][4] = {};

    // staging: per wave, rows w*32..w*32+31 of A and B; per k-half, lane i ->
    // row i/4, 16B chunk (i%4) in the 64-byte (32 x bf16) row. LDS dest is
    // uniform-base + lane*16 (global_load_lds constraint) -> row-major, no pad.
    const int srow = lane >> 2;
    const int scol = (lane & 3) * 8;
    const u16* gA0 = A + (size_t)(bm * 128 + w * 32 + srow) * K + scol;
    const u16* gA1 = gA0 + (size_t)16 * K;
    const u16* gB0 = B + (size_t)(bn * 128 + w * 32 + srow) * K + scol;
    const u16* gB1 = gB0 + (size_t)16 * K;
    u16* dA[2][2], * dB[2][2];
#pragma unroll
    for (int h = 0; h < 2; h++) {
        dA[h][0] = &lA[h][(w * 32) * 32];
        dA[h][1] = &lA[h][(w * 32 + 16) * 32];
        dB[h][0] = &lB[h][(w * 32) * 32];
        dB[h][1] = &lB[h][(w * 32 + 16) * 32];
    }

    for (int kt = 0; kt < K; kt += 64) {
        GLDS(gA0 + kt,      dA[0][0]);
        GLDS(gA1 + kt,      dA[0][1]);
        GLDS(gA0 + kt + 32, dA[1][0]);
        GLDS(gA1 + kt + 32, dA[1][1]);
        GLDS(gB0 + kt,      dB[0][0]);
        GLDS(gB1 + kt,      dB[0][1]);
        GLDS(gB0 + kt + 32, dB[1][0]);
        GLDS(gB1 + kt + 32, dB[1][1]);
        __syncthreads();   // one vmcnt(0) drain per 64-wide k-slab

#pragma unroll
        for (int h = 0; h < 2; h++) {
            short8 af[4], bf[4];
#pragma unroll
            for (int i = 0; i < 4; i++)
                af[i] = *(const short8*)&lA[h][(wm * 64 + i * 16 + r) * 32 + q * 8];
#pragma unroll
            for (int j = 0; j < 4; j++)
                bf[j] = *(const short8*)&lB[h][(wn * 64 + j * 16 + r) * 32 + q * 8];

#pragma unroll
            for (int i = 0; i < 4; i++)
#pragma unroll
                for (int j = 0; j < 4; j++)
                    acc[i][j] = __builtin_amdgcn_mfma_f32_16x16x32_bf16(
                        af[i], bf[j], acc[i][j], 0, 0, 0);
        }

        __syncthreads();
    }

    float pts = pts_from_amax(__uint_as_float(*amax_bits));

    // C/D layout (verified m89/m91): col = lane&15, row = (lane>>4)*4 + reg
    float* Cb = C + (size_t)(bm * 128 + wm * 64 + q * 4) * N + bn * 128 + wn * 64 + r;
#pragma unroll
    for (int i = 0; i < 4; i++)
#pragma unroll
        for (int j = 0; j < 4; j++)
#pragma unroll
            for (int t = 0; t < 4; t++)
                Cb[(size_t)(i * 16 + t) * N + j * 16] = pts * acc[i][j][t];
}

// ---- launch --------------------------------------------------------------

extern "C" void kernel_launch(void* const* d_in, const int* in_sizes, int n_in,
                              void* d_out, int out_size, void* d_ws, size_t ws_size,
                              hipStream_t stream) {
    const float* x   = (const float*)d_in[0];
    const int*   wp  = (const int*)d_in[1];
    const float* wsc = (const float*)d_in[2];
    const float* wgs = (const float*)d_in[3];
    float* out = (float*)d_out;

    // workspace layout:
    //   +0      : amax bits (u32, written by amax_fin)
    //   +64     : 2048 float partial maxima
    //   +16384  : A bf16 [M*K]
    //   then    : B bf16 [N*K]
    u32*   amax_ws = (u32*)d_ws;
    float* part    = (float*)((char*)d_ws + 64);
    u16*   aq      = (u16*)((char*)d_ws + 16384);
    u16*   wq      = aq + (size_t)M * K;

    amax_part<<<2048, 256, 0, stream>>>((const float4*)x, part, M * K / 4);
    amax_fin<<<1, 1024, 0, stream>>>(part, amax_ws);
    prep<<<QB + DB, 256, 0, stream>>>((const float4*)x, (uint2*)aq, amax_ws,
                                      wp, wsc, wgs, wq);
    gemm_bt<<<(M / 128) * (N / 128), 256, 0, stream>>>(aq, wq, out, amax_ws);
}